// Round 12
// baseline (241.404 us; speedup 1.0000x reference)
//
#include <hip/hip_runtime.h>

#define TILE_SHIFT 5     // 32x32-px tiles
#define NXCD 8
#define QUAD 64          // 2x2 tiles = one block's staged region
#define MARGIN 12        // drift margin: sigma ~8px over 60 steps
#define LDSF2 8064       // 63KB of float2; max window (64+24)^2=7744 fits

// ---------------------------------------------------------------------------
// Kernel 1 (unchanged, R11-verified): planar -> interleaved pre-scaled float2.
// ---------------------------------------------------------------------------
__global__ __launch_bounds__(256) void interleave_kernel(
    const float* __restrict__ dP, float2* __restrict__ im,
    int HW, float s0, float s1, int swz_on)
{
    int bid = blockIdx.x;
    if (swz_on) {
        int cpx = gridDim.x >> 3;
        bid = (bid & (NXCD - 1)) * cpx + (bid >> 3);
    }
    int i = bid * blockDim.x + threadIdx.x;
    int nquad = HW >> 2;
    if (i >= nquad) return;
    const float4* p0 = reinterpret_cast<const float4*>(dP);
    const float4* p1 = reinterpret_cast<const float4*>(dP + HW);
    float4 a = p1[i];
    float4 b = p0[i];
    float4 lo, hi;
    lo.x = a.x * s0; lo.y = b.x * s1; lo.z = a.y * s0; lo.w = b.y * s1;
    hi.x = a.z * s0; hi.y = b.z * s1; hi.z = a.w * s0; hi.w = b.w * s1;
    float4* outv = reinterpret_cast<float4*>(im);
    outv[2 * i]     = lo;
    outv[2 * i + 1] = hi;
}

// ---------------------------------------------------------------------------
// Binning, now Morton-keyed: bins [4q,4q+4) = one 64x64-px quad.
// ---------------------------------------------------------------------------
__global__ __launch_bounds__(256) void zero_kernel(int* __restrict__ p, int n)
{
    int i = blockIdx.x * blockDim.x + threadIdx.x;
    if (i < n) p[i] = 0;
}

__device__ __forceinline__ unsigned part1by1(unsigned x)
{
    x &= 0xFFFFu;
    x = (x | (x << 8)) & 0x00FF00FFu;
    x = (x | (x << 4)) & 0x0F0F0F0Fu;
    x = (x | (x << 2)) & 0x33333333u;
    x = (x | (x << 1)) & 0x55555555u;
    return x;
}
__device__ __forceinline__ unsigned compact1by1(unsigned x)
{
    x &= 0x55555555u;
    x = (x | (x >> 1)) & 0x33333333u;
    x = (x | (x >> 2)) & 0x0F0F0F0Fu;
    x = (x | (x >> 4)) & 0x00FF00FFu;
    x = (x | (x >> 8)) & 0x0000FFFFu;
    return x;
}

__device__ __forceinline__ int point_bin(const int* inds, int n, int N,
                                         int H, int W, int tiles_x, int use_morton)
{
    int y = inds[n];
    int x = inds[N + n];
    int ty = min(max(y, 0), H - 1) >> TILE_SHIFT;
    int tx = min(max(x, 0), W - 1) >> TILE_SHIFT;
    if (use_morton) return (int)(part1by1((unsigned)tx) | (part1by1((unsigned)ty) << 1));
    return ty * tiles_x + tx;
}

__global__ __launch_bounds__(256) void hist_kernel(
    const int* __restrict__ inds, int* __restrict__ hist,
    int N, int H, int W, int tiles_x, int use_morton)
{
    int n = blockIdx.x * blockDim.x + threadIdx.x;
    if (n >= N) return;
    atomicAdd(&hist[point_bin(inds, n, N, H, W, tiles_x, use_morton)], 1);
}

__global__ __launch_bounds__(1024) void scan_kernel(
    const int* __restrict__ hist, int* __restrict__ cursor, int ntiles)
{
    __shared__ int partial[1024];
    const int tid = threadIdx.x;
    const int items = (ntiles + 1023) >> 10;
    const int base = tid * items;
    int sum = 0;
    for (int i = 0; i < items; ++i) {
        int idx = base + i;
        if (idx < ntiles) sum += hist[idx];
    }
    partial[tid] = sum;
    __syncthreads();
    for (int off = 1; off < 1024; off <<= 1) {
        int v = (tid >= off) ? partial[tid - off] : 0;
        __syncthreads();
        partial[tid] += v;
        __syncthreads();
    }
    int excl = (tid == 0) ? 0 : partial[tid - 1];
    for (int i = 0; i < items; ++i) {
        int idx = base + i;
        if (idx < ntiles) {
            int h = hist[idx];
            cursor[idx] = excl;
            excl += h;
        }
    }
}

__global__ __launch_bounds__(256) void scatter_kernel(
    const int* __restrict__ inds, int* __restrict__ cursor,
    int* __restrict__ perm, int N, int H, int W, int tiles_x, int use_morton)
{
    int n = blockIdx.x * blockDim.x + threadIdx.x;
    if (n >= N) return;
    int slot = atomicAdd(&cursor[point_bin(inds, n, N, H, W, tiles_x, use_morton)], 1);
    perm[slot] = n;
}

// ---------------------------------------------------------------------------
// Quad-staged iteration: block q stages its 64x64 quad + 12px margin into LDS
// (exact float2 copies), then iterates its points. Per-corner window check;
// drifted-out points use the identical global read. FP order identical to
// the R11-verified kernel (fp contract off).
// ---------------------------------------------------------------------------
__global__ __launch_bounds__(256) void iterate_quad_kernel(
    const float2* __restrict__ im, const int* __restrict__ cursor,
    const int* __restrict__ perm, const int* __restrict__ inds,
    const int* __restrict__ niter_p, float* __restrict__ out,
    int H, int W, int N)
{
#pragma clang fp contract(off)
    __shared__ float2 win[LDSF2];
    const int q = blockIdx.x;
    const int qx = (int)compact1by1((unsigned)q);
    const int qy = (int)compact1by1((unsigned)q >> 1);
    const int wx0 = max(qx * QUAD - MARGIN, 0);
    const int wy0 = max(qy * QUAD - MARGIN, 0);
    const int wx1 = min(qx * QUAD + QUAD + MARGIN, W);
    const int wy1 = min(qy * QUAD + QUAD + MARGIN, H);
    const int wcols = wx1 - wx0, wrows = wy1 - wy0;
    const int nwin = wcols * wrows;   // <= 7744

    // ---- stage window (incremental div-free row/col walk) ----------------
    {
        int idx = threadIdx.x;
        int r = idx / wcols;              // one division
        int c = idx - r * wcols;
        while (idx < nwin) {
            win[idx] = im[(size_t)(wy0 + r) * W + wx0 + c];
            idx += 256;
            c += 256;
            while (c >= wcols) { c -= wcols; ++r; }
        }
    }
    __syncthreads();

    const int start = (q == 0) ? 0 : cursor[4 * q - 1];
    const int end   = cursor[4 * q + 3];
    const int niter = niter_p[0];
    const float sH = (float)(H - 1);
    const float sW = (float)(W - 1);
    const float Wf = (float)W, Hf = (float)H;

    for (int s = start + (int)threadIdx.x; s < end; s += 256) {
        const int pid = perm[s];
        float px = ((float)inds[N + pid] / sH) * 2.0f - 1.0f;
        float py = ((float)inds[pid]     / sW) * 2.0f - 1.0f;

        for (int it = 0; it < niter; ++it) {
            float x = ((px + 1.0f) * Wf - 1.0f) * 0.5f;
            float y = ((py + 1.0f) * Hf - 1.0f) * 0.5f;
            float x0f = floorf(x), y0f = floorf(y);
            float wx1f = x - x0f,  wy1f = y - y0f;
            float wx0f = 1.0f - wx1f, wy0f = 1.0f - wy1f;
            int x0 = (int)x0f, y0 = (int)y0f;
            int x1 = x0 + 1,   y1 = y0 + 1;

            int x0c = min(max(x0, 0), W - 1);
            int x1c = min(max(x1, 0), W - 1);
            int y0c = min(max(y0, 0), H - 1);
            int y1c = min(max(y1, 0), H - 1);
            bool bx0 = (x0 >= 0) & (x0 < W);
            bool bx1 = (x1 >= 0) & (x1 < W);
            bool by0 = (y0 >= 0) & (y0 < H);
            bool by1 = (y1 >= 0) & (y1 < H);

            float2 v00, v10, v01, v11;
            bool inwin = (x0c >= wx0) & (x1c < wx1) & (y0c >= wy0) & (y1c < wy1);
            if (inwin) {
                int cx0 = x0c - wx0, cx1 = x1c - wx0;
                int ry0 = (y0c - wy0) * wcols, ry1 = (y1c - wy0) * wcols;
                v00 = win[ry0 + cx0]; v10 = win[ry0 + cx1];
                v01 = win[ry1 + cx0]; v11 = win[ry1 + cx1];
            } else {
                const float2* r0 = im + (size_t)y0c * W;
                const float2* r1 = im + (size_t)y1c * W;
                v00 = r0[x0c]; v10 = r0[x1c];
                v01 = r1[x0c]; v11 = r1[x1c];
            }
            const float2 zero = make_float2(0.0f, 0.0f);
            if (!(bx0 & by0)) v00 = zero;
            if (!(bx1 & by0)) v10 = zero;
            if (!(bx0 & by1)) v01 = zero;
            if (!(bx1 & by1)) v11 = zero;

            float w00 = wx0f * wy0f, w10 = wx1f * wy0f;
            float w01 = wx0f * wy1f, w11 = wx1f * wy1f;
            float dx = ((v00.x * w00 + v10.x * w10) + v01.x * w01) + v11.x * w11;
            float dy = ((v00.y * w00 + v10.y * w10) + v01.y * w01) + v11.y * w11;

            px = fminf(fmaxf(px + dx, -1.0f), 1.0f);
            py = fminf(fmaxf(py + dy, -1.0f), 1.0f);
        }

        out[pid]     = (py + 1.0f) * 0.5f * sW;
        out[N + pid] = (px + 1.0f) * 0.5f * sH;
    }
}

// ---------------------------------------------------------------------------
// Fallback iterate (R11-verified structure) for shapes the quad path can't
// take, or tiny ws.  MODE 1: interleaved image.  MODE 0: planar dP.
// ---------------------------------------------------------------------------
template <int MODE>
__global__ __launch_bounds__(256) void iterate1_kernel(
    const float2* __restrict__ im, const float* __restrict__ dP,
    const int* __restrict__ inds, const int* __restrict__ niter_p,
    float* __restrict__ out, int H, int W, int N)
{
#pragma clang fp contract(off)
    const int t = blockIdx.x * blockDim.x + threadIdx.x;
    if (t >= N) return;
    const int niter = niter_p[0];
    const float sH = (float)(H - 1);
    const float sW = (float)(W - 1);
    const float s0 = 2.0f / sH;
    const float s1 = 2.0f / sW;
    const int HW = H * W;
    const float Wf = (float)W, Hf = (float)H;

    float px = ((float)inds[N + t] / sH) * 2.0f - 1.0f;
    float py = ((float)inds[t]     / sW) * 2.0f - 1.0f;

    for (int it = 0; it < niter; ++it) {
        float x = ((px + 1.0f) * Wf - 1.0f) * 0.5f;
        float y = ((py + 1.0f) * Hf - 1.0f) * 0.5f;
        float x0f = floorf(x), y0f = floorf(y);
        float wx1 = x - x0f,  wy1 = y - y0f;
        float wx0 = 1.0f - wx1, wy0 = 1.0f - wy1;
        int x0 = (int)x0f, y0 = (int)y0f;
        int x1 = x0 + 1,   y1 = y0 + 1;

        int x0c = min(max(x0, 0), W - 1);
        int x1c = min(max(x1, 0), W - 1);
        int y0c = min(max(y0, 0), H - 1);
        int y1c = min(max(y1, 0), H - 1);
        bool bx0 = (x0 >= 0) & (x0 < W);
        bool bx1 = (x1 >= 0) & (x1 < W);
        bool by0 = (y0 >= 0) & (y0 < H);
        bool by1 = (y1 >= 0) & (y1 < H);

        float2 v00, v10, v01, v11;
        if (MODE >= 1) {
            const float2* r0 = im + (size_t)y0c * W;
            const float2* r1 = im + (size_t)y1c * W;
            v00 = r0[x0c]; v10 = r0[x1c];
            v01 = r1[x0c]; v11 = r1[x1c];
        } else {
            int i00 = y0c * W + x0c, i10 = y0c * W + x1c;
            int i01 = y1c * W + x0c, i11 = y1c * W + x1c;
            v00 = make_float2(dP[HW + i00] * s0, dP[i00] * s1);
            v10 = make_float2(dP[HW + i10] * s0, dP[i10] * s1);
            v01 = make_float2(dP[HW + i01] * s0, dP[i01] * s1);
            v11 = make_float2(dP[HW + i11] * s0, dP[i11] * s1);
        }
        const float2 zero = make_float2(0.0f, 0.0f);
        if (!(bx0 & by0)) v00 = zero;
        if (!(bx1 & by0)) v10 = zero;
        if (!(bx0 & by1)) v01 = zero;
        if (!(bx1 & by1)) v11 = zero;

        float w00 = wx0 * wy0, w10 = wx1 * wy0;
        float w01 = wx0 * wy1, w11 = wx1 * wy1;
        float dx = ((v00.x * w00 + v10.x * w10) + v01.x * w01) + v11.x * w11;
        float dy = ((v00.y * w00 + v10.y * w10) + v01.y * w01) + v11.y * w11;

        px = fminf(fmaxf(px + dx, -1.0f), 1.0f);
        py = fminf(fmaxf(py + dy, -1.0f), 1.0f);
    }

    out[t]     = (py + 1.0f) * 0.5f * sW;
    out[N + t] = (px + 1.0f) * 0.5f * sH;
}

extern "C" void kernel_launch(void* const* d_in, const int* in_sizes, int n_in,
                              void* d_out, int out_size, void* d_ws, size_t ws_size,
                              hipStream_t stream) {
    const float* dP      = (const float*)d_in[0];
    const int*   inds    = (const int*)d_in[1];
    const int*   niter_p = (const int*)d_in[2];
    float*       out     = (float*)d_out;

    const int HW = in_sizes[0] / 2;
    int W = 1;
    while ((long long)W * W < (long long)HW) W <<= 1;  // 4194304 -> 2048
    const int H = HW / W;
    const int N = in_sizes[1] / 2;

    const float s0 = 2.0f / (float)(H - 1);
    const float s1 = 2.0f / (float)(W - 1);

    const int tiles_x = ((W - 1) >> TILE_SHIFT) + 1;
    const int tiles_y = ((H - 1) >> TILE_SHIFT) + 1;
    const int ntiles  = tiles_x * tiles_y;

    // quad path: square pow2 tile grid with >=2 tiles per axis
    const bool quadOK = (tiles_x == tiles_y) && (tiles_x >= 2) &&
                        ((tiles_x & (tiles_x - 1)) == 0);
    const int nquads = quadOK ? (tiles_x >> 1) * (tiles_y >> 1) : 0;

    const size_t im_bytes   = (size_t)HW * sizeof(float2);
    const size_t perm_bytes = (size_t)N * sizeof(int);
    const size_t aux_bytes  = (size_t)2 * ntiles * sizeof(int);

    char* base = (char*)d_ws;
    float2* im     = (float2*)base;
    int*    perm   = (int*)(base + im_bytes);
    int*    hist   = (int*)(base + im_bytes + perm_bytes);
    int*    cursor = hist + ntiles;

    const int nblkN  = (N + 255) / 256;
    const int nblkIm = (HW / 4 + 255) / 256;
    const int swzIm  = (nblkIm % NXCD) == 0 && (HW / 4) % 256 == 0;

    if (quadOK && ws_size >= im_bytes + perm_bytes + aux_bytes) {
        interleave_kernel<<<nblkIm, 256, 0, stream>>>(dP, im, HW, s0, s1, swzIm);
        zero_kernel<<<(ntiles + 255) / 256, 256, 0, stream>>>(hist, ntiles);
        hist_kernel<<<nblkN, 256, 0, stream>>>(inds, hist, N, H, W, tiles_x, 1);
        scan_kernel<<<1, 1024, 0, stream>>>(hist, cursor, ntiles);
        scatter_kernel<<<nblkN, 256, 0, stream>>>(inds, cursor, perm, N, H, W, tiles_x, 1);
        iterate_quad_kernel<<<nquads, 256, 0, stream>>>(
            im, cursor, perm, inds, niter_p, out, H, W, N);
    } else if (ws_size >= im_bytes) {
        interleave_kernel<<<nblkIm, 256, 0, stream>>>(dP, im, HW, s0, s1, swzIm);
        iterate1_kernel<1><<<nblkN, 256, 0, stream>>>(
            im, dP, inds, niter_p, out, H, W, N);
    } else {
        iterate1_kernel<0><<<nblkN, 256, 0, stream>>>(
            nullptr, dP, inds, niter_p, out, H, W, N);
    }
}